// Round 6
// baseline (1271.340 us; speedup 1.0000x reference)
//
#include <hip/hip_runtime.h>

typedef float f4   __attribute__((ext_vector_type(4)));
typedef float f2   __attribute__((ext_vector_type(2)));
typedef short bf16x8 __attribute__((ext_vector_type(8)));
typedef float f32x4  __attribute__((ext_vector_type(4)));

#define N_ROWS  32768
#define D_DIM   256
#define K_CODES 8192
#define NUM_ELEM (N_ROWS * D_DIM)
#define EPS_MARGIN 1e-3f     // proven in R2-R5
#define FB_CAP  8192
#define FB_RPB  8
#define RF_SLICES 16
#define N_PANELS 512         // 16 codes per panel
#define QTR_PANELS 128       // panels per code-quarter (2048 codes)

__device__ __forceinline__ short f2bf(float f) {
    union { float f; unsigned u; } v; v.f = f;
    unsigned r = v.u + 0x7FFFu + ((v.u >> 16) & 1u);
    return (short)(r >> 16);
}
__device__ __forceinline__ float bf2f(short h) {
    union { unsigned u; float f; } v; v.u = ((unsigned)(unsigned short)h) << 16;
    return v.f;
}
__device__ __forceinline__ void gl2lds16(const void* g, void* l) {
    __builtin_amdgcn_global_load_lds(
        (const __attribute__((address_space(1))) unsigned int*)g,
        (__attribute__((address_space(3))) unsigned int*)l, 16, 0, 0);
}

// -------- ee[k] = sum_d E[d][k]^2 --------
__global__ void ee_kernel(const float* __restrict__ E, float* __restrict__ ee) {
    const int k = blockIdx.x * blockDim.x + threadIdx.x;
    double s = 0.0;
    for (int d = 0; d < D_DIM; ++d) {
        float v = E[(size_t)d * K_CODES + k];
        s += (double)v * (double)v;
    }
    ee[k] = (float)s;
}

// -------- Ep: panel-major bf16 h/l split; panel = 16 codes (16 KB, LDS image) --------
// panel p shorts [p*8192,+8192): h granule (g,c) at (g*16+c)*8, l at +4096
__global__ void prep_kernel(const float* __restrict__ E, short* __restrict__ Ep) {
    const int p  = blockIdx.x;         // 0..511
    const int t  = threadIdx.x;
    const int c  = t & 15;
    const int gq = t >> 4;             // 0..15, 2 granules each
    const int cp = p * 16;
    short* ph = Ep + (size_t)p * 8192;
    short* pl = ph + 4096;
    #pragma unroll
    for (int gi = 0; gi < 2; ++gi) {
        int g = gq * 2 + gi;
        bf16x8 h, l;
        #pragma unroll
        for (int j = 0; j < 8; ++j) {
            float v = E[(size_t)(g * 8 + j) * K_CODES + cp + c];
            short hh = f2bf(v);
            h[j] = hh;
            l[j] = f2bf(v - bf2f(hh));
        }
        *(bf16x8*)(ph + (g * 16 + c) * 8) = h;
        *(bf16x8*)(pl + (g * 16 + c) * 8) = l;
    }
}

// -------- Et32[k][d] = E[d][k] --------
__global__ void trans32_kernel(const float* __restrict__ E, float* __restrict__ Et32) {
    __shared__ float tile[64][65];
    const int t  = threadIdx.x;
    const int k0 = blockIdx.x * 64, d0 = blockIdx.y * 64;
    #pragma unroll
    for (int i = 0; i < 16; ++i) {
        int dd = i * 4 + (t >> 6), kk = t & 63;
        tile[dd][kk] = E[(size_t)(d0 + dd) * K_CODES + k0 + kk];
    }
    __syncthreads();
    #pragma unroll
    for (int i = 0; i < 16; ++i) {
        int kk = i * 4 + (t >> 6), dd = t & 63;
        Et32[(size_t)(k0 + kk) * D_DIM + d0 + dd] = tile[dd][kk];
    }
}

// -------- MFMA sieve: grid 1024 = (row-tile 256) x (code-quarter 4) --------
__launch_bounds__(256, 4)
__global__ void mfma_sieve_kernel(const float* __restrict__ X,
                                  const short* __restrict__ Ep,
                                  const float* __restrict__ ee,
                                  f2* __restrict__ res_bs,     // [row*4+q] = (best, sec)
                                  int* __restrict__ res_idx) { // [row*4+q]
    __shared__ __align__(16) short Bbuf[2][8192];   // 2 x 16 KB
    const int t    = threadIdx.x;
    const int w    = t >> 6;
    const int lane = t & 63;
    const int n    = lane & 15;
    const int quad = lane >> 4;
    const int qtr  = blockIdx.x & 3;
    const int row0 = (blockIdx.x >> 2) * 128;
    const int rw   = row0 + w * 32;
    const int p0   = qtr * QTR_PANELS;

    // ---- A fragments (32 rows x 256 d, h+l) -> registers (identical to R3-R5) ----
    bf16x8 Ah[2][8], Al[2][8];
    #pragma unroll
    for (int rt = 0; rt < 2; ++rt) {
        const float* xp = X + (size_t)(rw + rt * 16 + n) * D_DIM;
        #pragma unroll
        for (int ks = 0; ks < 8; ++ks) {
            int d = ks * 32 + quad * 8;
            f4 a = *(const f4*)(xp + d);
            f4 b = *(const f4*)(xp + d + 4);
            bf16x8 h, l;
            #pragma unroll
            for (int j = 0; j < 8; ++j) {
                float x = (j < 4) ? a[j] : b[j - 4];
                short hh = f2bf(x);
                h[j] = hh;
                l[j] = f2bf(x - bf2f(hh));
            }
            Ah[rt][ks] = h; Al[rt][ks] = l;
        }
    }

    float bestv[8], secv[8]; int besti[8];
    #pragma unroll
    for (int s = 0; s < 8; ++s) { bestv[s] = 1e30f; secv[s] = 1e30f; besti[s] = 0; }

    {   // prime panel p0 -> buf 0 (16 KB: 16 x 1KB, 4 per wave)
        const char* gp = (const char*)Ep + (size_t)p0 * 16384;
        char* lp = (char*)&Bbuf[0][0];
        #pragma unroll
        for (int i = 0; i < 4; ++i)
            gl2lds16(gp + (w * 4 + i) * 1024 + lane * 16, lp + (w * 4 + i) * 1024);
    }
    __syncthreads();

    for (int i = 0; i < QTR_PANELS; ++i) {
        const int p   = p0 + i;
        const int buf = i & 1;
        if (i + 1 < QTR_PANELS) {
            const char* gp = (const char*)Ep + (size_t)(p + 1) * 16384;
            char* lp = (char*)&Bbuf[buf ^ 1][0];
            #pragma unroll
            for (int k = 0; k < 4; ++k)
                gl2lds16(gp + (w * 4 + k) * 1024 + lane * 16, lp + (w * 4 + k) * 1024);
        }

        const short* Bh = &Bbuf[buf][0];
        const short* Bl = &Bbuf[buf][4096];

        f32x4 acc[2];                  // [rt]
        acc[0] = (f32x4)(0.0f);
        acc[1] = (f32x4)(0.0f);

        #pragma unroll
        for (int ks = 0; ks < 8; ++ks) {
            const int g = ks * 4 + quad;
            bf16x8 bh = *(const bf16x8*)(Bh + (g * 16 + n) * 8);
            bf16x8 bl = *(const bf16x8*)(Bl + (g * 16 + n) * 8);
            #pragma unroll
            for (int rt = 0; rt < 2; ++rt) {
                acc[rt] = __builtin_amdgcn_mfma_f32_16x16x32_bf16(Ah[rt][ks], bh, acc[rt], 0, 0, 0);
                acc[rt] = __builtin_amdgcn_mfma_f32_16x16x32_bf16(Al[rt][ks], bh, acc[rt], 0, 0, 0);
                acc[rt] = __builtin_amdgcn_mfma_f32_16x16x32_bf16(Ah[rt][ks], bl, acc[rt], 0, 0, 0);
            }
        }

        const int code = p * 16 + n;
        const float eev = ee[code];
        #pragma unroll
        for (int rt = 0; rt < 2; ++rt)
            #pragma unroll
            for (int r = 0; r < 4; ++r) {
                float key = fmaf(-2.0f, acc[rt][r], eev);
                int s = rt * 4 + r;
                float nb = fminf(key, bestv[s]);
                secv[s]  = fminf(secv[s], fmaxf(key, bestv[s]));
                besti[s] = (key < bestv[s]) ? code : besti[s];
                bestv[s] = nb;
            }
        __syncthreads();
    }

    // top-2 merge across the 16 'n' lanes
    #pragma unroll
    for (int off = 1; off < 16; off <<= 1) {
        #pragma unroll
        for (int s = 0; s < 8; ++s) {
            float ov = __shfl_xor(bestv[s], off);
            int   oi = __shfl_xor(besti[s], off);
            float os = __shfl_xor(secv[s], off);
            bool owin = (ov < bestv[s]) || (ov == bestv[s] && oi < besti[s]);
            if (owin) { secv[s] = fminf(os, bestv[s]); bestv[s] = ov; besti[s] = oi; }
            else      { secv[s] = fminf(secv[s], ov); }
        }
    }

    if (n == 0) {
        #pragma unroll
        for (int s = 0; s < 8; ++s) {
            int rl  = w * 32 + (s >> 2) * 16 + quad * 4 + (s & 3);
            int row = row0 + rl;
            f2 bs; bs[0] = bestv[s]; bs[1] = secv[s];
            res_bs[(size_t)row * 4 + qtr]  = bs;
            res_idx[(size_t)row * 4 + qtr] = besti[s];
        }
    }
}

// -------- merge quarters: final bidx + EPS flagging --------
__global__ void merge_kernel(const f2* __restrict__ res_bs, const int* __restrict__ res_idx,
                             int* __restrict__ bidx, int* __restrict__ counter,
                             int2* __restrict__ list) {
    const int row = blockIdx.x * blockDim.x + threadIdx.x;
    if (row >= N_ROWS) return;
    f2 c0 = res_bs[(size_t)row * 4];
    float gb = c0[0], gs = c0[1];
    int gi = res_idx[(size_t)row * 4];
    #pragma unroll
    for (int q = 1; q < 4; ++q) {        // ascending quarter: lowest-index ties
        f2 cq = res_bs[(size_t)row * 4 + q];
        int iq = res_idx[(size_t)row * 4 + q];
        if (cq[0] < gb) { gs = fminf(cq[1], gb); gb = cq[0]; gi = iq; }
        else            { gs = fminf(gs, cq[0]); }
    }
    bidx[row] = gi;
    if (gs - gb <= EPS_MARGIN) {
        int pos = atomicAdd(counter, 1);
        if (pos < FB_CAP) list[pos] = make_int2(row, gi);
    }
}

// -------- gather + straight-through output + loss (same op order as R4/R5) --------
__global__ void gather_kernel(const float* __restrict__ X, const float* __restrict__ Et32,
                              const int* __restrict__ bidx, float* __restrict__ out,
                              double* __restrict__ loss_sum) {
    __shared__ int bl_[128];
    const int t    = threadIdx.x;
    const int row0 = blockIdx.x * 128;
    if (t < 128) bl_[t] = bidx[row0 + t];
    __syncthreads();
    double ls = 0.0;
    const int d = t;
    #pragma unroll 4
    for (int r = 0; r < 128; ++r) {
        int code = bl_[r];
        float q  = Et32[(size_t)code * D_DIM + d];
        float x  = X[(size_t)(row0 + r) * D_DIM + d];
        float dq = q - x;
        out[(size_t)(row0 + r) * D_DIM + d] = x + dq;
        ls += (double)dq * (double)dq;
    }
    #pragma unroll
    for (int off = 32; off > 0; off >>= 1)
        ls += __shfl_down(ls, off);
    if ((t & 63) == 0) atomicAdd(loss_sum, ls);
}

// -------- refine phase 1: fp64 keys over (row-chunk x 16 slices) --------
__global__ void refine1_kernel(const float* __restrict__ X, const float* __restrict__ E,
                               const int* __restrict__ counter, const int2* __restrict__ list,
                               double* __restrict__ res_v, int* __restrict__ res_i) {
    __shared__ float xt[D_DIM][FB_RPB];
    __shared__ int rows_sh[FB_RPB];
    __shared__ double wbv[4][FB_RPB];
    __shared__ int    wbi[4][FB_RPB];

    int nf = *counter; if (nf > FB_CAP) nf = FB_CAP;
    const int nchunks = (nf + FB_RPB - 1) / FB_RPB;
    const int nitems  = nchunks * RF_SLICES;
    const int t = threadIdx.x;

    for (int item = blockIdx.x; item < nitems; item += gridDim.x) {
        const int rc = item / RF_SLICES;
        const int sl = item % RF_SLICES;
        __syncthreads();
        if (t < FB_RPB) {
            int e = rc * FB_RPB + t;
            int2 ent = list[(e < nf) ? e : 0];
            rows_sh[t] = ent.x;
        }
        __syncthreads();
        #pragma unroll
        for (int j = 0; j < FB_RPB; ++j)
            xt[t][j] = X[(size_t)rows_sh[j] * D_DIM + t];
        __syncthreads();

        const int k0 = sl * 512 + t * 2;
        double s0[FB_RPB], s1[FB_RPB], q0 = 0.0, q1 = 0.0;
        #pragma unroll
        for (int j = 0; j < FB_RPB; ++j) { s0[j] = 0.0; s1[j] = 0.0; }
        for (int d = 0; d < D_DIM; ++d) {
            f2 ev = *(const f2*)(E + (size_t)d * K_CODES + k0);
            double e0d = (double)ev[0], e1d = (double)ev[1];
            const f4* xp = (const f4*)(&xt[d][0]);
            f4 xa = xp[0], xb = xp[1];
            double xd[FB_RPB] = { (double)xa[0], (double)xa[1], (double)xa[2], (double)xa[3],
                                  (double)xb[0], (double)xb[1], (double)xb[2], (double)xb[3] };
            q0 += e0d * e0d; q1 += e1d * e1d;
            #pragma unroll
            for (int j = 0; j < FB_RPB; ++j) {
                s0[j] += xd[j] * e0d;
                s1[j] += xd[j] * e1d;
            }
        }
        double bv[FB_RPB]; int bi[FB_RPB];
        #pragma unroll
        for (int j = 0; j < FB_RPB; ++j) {
            double k0v = q0 - 2.0 * s0[j];
            double k1v = q1 - 2.0 * s1[j];
            bv[j] = k0v; bi[j] = k0;
            if (k1v < bv[j]) { bv[j] = k1v; bi[j] = k0 + 1; }
        }
        #pragma unroll
        for (int off = 1; off < 64; off <<= 1) {
            #pragma unroll
            for (int j = 0; j < FB_RPB; ++j) {
                double ov = __shfl_xor(bv[j], off);
                int    oi = __shfl_xor(bi[j], off);
                if (ov < bv[j] || (ov == bv[j] && oi < bi[j])) { bv[j] = ov; bi[j] = oi; }
            }
        }
        const int wave = t >> 6;
        if ((t & 63) == 0) {
            #pragma unroll
            for (int j = 0; j < FB_RPB; ++j) { wbv[wave][j] = bv[j]; wbi[wave][j] = bi[j]; }
        }
        __syncthreads();
        if (t < FB_RPB) {
            double b = wbv[0][t]; int i_ = wbi[0][t];
            #pragma unroll
            for (int wv = 1; wv < 4; ++wv) {
                double ov = wbv[wv][t]; int oi = wbi[wv][t];
                if (ov < b || (ov == b && oi < i_)) { b = ov; i_ = oi; }
            }
            int e = rc * FB_RPB + t;
            res_v[(size_t)e * RF_SLICES + sl] = b;
            res_i[(size_t)e * RF_SLICES + sl] = i_;
        }
    }
}

// -------- refine phase 2: pick fp64 winner, patch row + loss --------
__global__ void patch_kernel(const float* __restrict__ X, const float* __restrict__ Et32,
                             float* __restrict__ out, double* __restrict__ loss_sum,
                             const int* __restrict__ counter, const int2* __restrict__ list,
                             const double* __restrict__ res_v, const int* __restrict__ res_i) {
    int nf = *counter; if (nf > FB_CAP) nf = FB_CAP;
    const int b = blockIdx.x;
    if (b >= nf) return;
    __shared__ int nc_sh;
    const int t = threadIdx.x;
    if (t == 0) {
        double bv = res_v[(size_t)b * RF_SLICES]; int bi = res_i[(size_t)b * RF_SLICES];
        for (int s = 1; s < RF_SLICES; ++s) {
            double v = res_v[(size_t)b * RF_SLICES + s];
            int    i = res_i[(size_t)b * RF_SLICES + s];
            if (v < bv || (v == bv && i < bi)) { bv = v; bi = i; }
        }
        nc_sh = bi;
    }
    __syncthreads();
    int2 ent = list[b];
    const int oc = ent.y, row = ent.x, nc = nc_sh;
    if (nc == oc) return;
    float x  = X[(size_t)row * D_DIM + t];
    float qn = Et32[(size_t)nc * D_DIM + t];
    float qo = Et32[(size_t)oc * D_DIM + t];
    float dqn = qn - x, dqo = qo - x;
    out[(size_t)row * D_DIM + t] = x + dqn;
    double dl = (double)dqn * dqn - (double)dqo * dqo;
    #pragma unroll
    for (int off = 32; off > 0; off >>= 1)
        dl += __shfl_down(dl, off);
    if ((t & 63) == 0) atomicAdd(loss_sum, dl);
}

// -------- finalize loss --------
__global__ void fin_kernel(const double* __restrict__ loss_sum, float* __restrict__ out) {
    double m = loss_sum[0] / (double)NUM_ELEM;
    out[NUM_ELEM] = (float)(0.25 * m + m);
}

extern "C" void kernel_launch(void* const* d_in, const int* in_sizes, int n_in,
                              void* d_out, int out_size, void* d_ws, size_t ws_size,
                              hipStream_t stream) {
    const float* X = (const float*)d_in[0];   // [32,1024,256] fp32
    const float* E = (const float*)d_in[1];   // [256,8192] fp32
    float* out = (float*)d_out;

    // ws layout (res_bs/res_idx are dead after merge -> reused as res_v/res_i)
    double* loss_sum = (double*)d_ws;                          // 8 B
    int*    counter  = (int*)((char*)d_ws + 8);                // 4 B
    float*  ee       = (float*)((char*)d_ws + 1024);           // 32 KB
    int2*   list     = (int2*)((char*)d_ws + 36864);           // 64 KB
    f2*     res_bs   = (f2*)((char*)d_ws + 131072);            // 1 MB (131072 x f2)
    double* res_v    = (double*)((char*)d_ws + 131072);        // aliases res_bs
    int*    res_idx  = (int*)((char*)d_ws + 1179648);          // 512 KB
    int*    res_i    = (int*)((char*)d_ws + 1179648);          // aliases res_idx
    int*    bidx     = (int*)((char*)d_ws + 1703936);          // 128 KB
    float*  Et32     = (float*)((char*)d_ws + 1835008);        // 8 MB
    short*  Ep       = (short*)((char*)d_ws + 10223616);       // 8 MB -> ends ~17.8 MB

    hipMemsetAsync(d_ws, 0, 1024, stream);
    prep_kernel<<<N_PANELS, 256, 0, stream>>>(E, Ep);
    trans32_kernel<<<dim3(128, 4), 256, 0, stream>>>(E, Et32);
    ee_kernel<<<K_CODES / 256, 256, 0, stream>>>(E, ee);
    mfma_sieve_kernel<<<1024, 256, 0, stream>>>(X, Ep, ee, res_bs, res_idx);
    merge_kernel<<<N_ROWS / 256, 256, 0, stream>>>(res_bs, res_idx, bidx, counter, list);
    gather_kernel<<<N_ROWS / 128, 256, 0, stream>>>(X, Et32, bidx, out, loss_sum);
    refine1_kernel<<<2048, 256, 0, stream>>>(X, E, counter, list, res_v, res_i);
    patch_kernel<<<FB_CAP, 256, 0, stream>>>(X, Et32, out, loss_sum, counter, list,
                                             res_v, res_i);
    fin_kernel<<<1, 1, 0, stream>>>(loss_sum, out);
}

// Round 7
// 544.431 us; speedup vs baseline: 2.3352x; 2.3352x over previous
//
#include <hip/hip_runtime.h>

typedef float f4   __attribute__((ext_vector_type(4)));
typedef float f2   __attribute__((ext_vector_type(2)));
typedef short bf16x8 __attribute__((ext_vector_type(8)));
typedef float f32x4  __attribute__((ext_vector_type(4)));

#define N_ROWS  32768
#define D_DIM   256
#define K_CODES 8192
#define NUM_ELEM (N_ROWS * D_DIM)
#define EPS_MARGIN 1e-3f     // proven in R2-R6
#define FB_CAP  8192
#define FB_RPB  8
#define RF_SLICES 16
#define N_PANELS 512         // 16 codes per panel
#define QTR_PANELS 128       // panels per code-quarter (2048 codes)

__device__ __forceinline__ short f2bf(float f) {
    union { float f; unsigned u; } v; v.f = f;
    unsigned r = v.u + 0x7FFFu + ((v.u >> 16) & 1u);
    return (short)(r >> 16);
}
__device__ __forceinline__ float bf2f(short h) {
    union { unsigned u; float f; } v; v.u = ((unsigned)(unsigned short)h) << 16;
    return v.f;
}
__device__ __forceinline__ void gl2lds16(const void* g, void* l) {
    __builtin_amdgcn_global_load_lds(
        (const __attribute__((address_space(1))) unsigned int*)g,
        (__attribute__((address_space(3))) unsigned int*)l, 16, 0, 0);
}

// -------- ee[k] = sum_d E[d][k]^2 --------
__global__ void ee_kernel(const float* __restrict__ E, float* __restrict__ ee) {
    const int k = blockIdx.x * blockDim.x + threadIdx.x;
    double s = 0.0;
    for (int d = 0; d < D_DIM; ++d) {
        float v = E[(size_t)d * K_CODES + k];
        s += (double)v * (double)v;
    }
    ee[k] = (float)s;
}

// -------- Ep: panel-major bf16 h/l split; panel = 16 codes (16 KB, LDS image) --------
__global__ void prep_kernel(const float* __restrict__ E, short* __restrict__ Ep) {
    const int p  = blockIdx.x;         // 0..511
    const int t  = threadIdx.x;
    const int c  = t & 15;
    const int gq = t >> 4;             // 0..15, 2 granules each
    const int cp = p * 16;
    short* ph = Ep + (size_t)p * 8192;
    short* pl = ph + 4096;
    #pragma unroll
    for (int gi = 0; gi < 2; ++gi) {
        int g = gq * 2 + gi;
        bf16x8 h, l;
        #pragma unroll
        for (int j = 0; j < 8; ++j) {
            float v = E[(size_t)(g * 8 + j) * K_CODES + cp + c];
            short hh = f2bf(v);
            h[j] = hh;
            l[j] = f2bf(v - bf2f(hh));
        }
        *(bf16x8*)(ph + (g * 16 + c) * 8) = h;
        *(bf16x8*)(pl + (g * 16 + c) * 8) = l;
    }
}

// -------- Et32[k][d] = E[d][k] --------
__global__ void trans32_kernel(const float* __restrict__ E, float* __restrict__ Et32) {
    __shared__ float tile[64][65];
    const int t  = threadIdx.x;
    const int k0 = blockIdx.x * 64, d0 = blockIdx.y * 64;
    #pragma unroll
    for (int i = 0; i < 16; ++i) {
        int dd = i * 4 + (t >> 6), kk = t & 63;
        tile[dd][kk] = E[(size_t)(d0 + dd) * K_CODES + k0 + kk];
    }
    __syncthreads();
    #pragma unroll
    for (int i = 0; i < 16; ++i) {
        int kk = i * 4 + (t >> 6), dd = t & 63;
        Et32[(size_t)(k0 + kk) * D_DIM + d0 + dd] = tile[dd][kk];
    }
}

// -------- MFMA sieve: grid 1024 = (row-tile 256) x (code-quarter 4) --------
// __launch_bounds__(256,2): R6's (256,4) clamped VGPR to 64 -> A-frag scratch
// spill -> 3.5 GB FETCH. (256,2) gives VGPR~128; HW still fits 4 blocks/CU.
__launch_bounds__(256, 2)
__global__ void mfma_sieve_kernel(const float* __restrict__ X,
                                  const short* __restrict__ Ep,
                                  const float* __restrict__ ee,
                                  f2* __restrict__ res_bs,     // [row*4+q] = (best, sec)
                                  int* __restrict__ res_idx) { // [row*4+q]
    __shared__ __align__(16) short Bbuf[2][8192];   // 2 x 16 KB
    const int t    = threadIdx.x;
    const int w    = t >> 6;
    const int lane = t & 63;
    const int n    = lane & 15;
    const int quad = lane >> 4;
    const int qtr  = blockIdx.x & 3;
    const int row0 = (blockIdx.x >> 2) * 128;
    const int rw   = row0 + w * 32;
    const int p0   = qtr * QTR_PANELS;

    // ---- A fragments (32 rows x 256 d, h+l) -> registers (identical to R3-R6) ----
    bf16x8 Ah[2][8], Al[2][8];
    #pragma unroll
    for (int rt = 0; rt < 2; ++rt) {
        const float* xp = X + (size_t)(rw + rt * 16 + n) * D_DIM;
        #pragma unroll
        for (int ks = 0; ks < 8; ++ks) {
            int d = ks * 32 + quad * 8;
            f4 a = *(const f4*)(xp + d);
            f4 b = *(const f4*)(xp + d + 4);
            bf16x8 h, l;
            #pragma unroll
            for (int j = 0; j < 8; ++j) {
                float x = (j < 4) ? a[j] : b[j - 4];
                short hh = f2bf(x);
                h[j] = hh;
                l[j] = f2bf(x - bf2f(hh));
            }
            Ah[rt][ks] = h; Al[rt][ks] = l;
        }
    }

    float bestv[8], secv[8]; int besti[8];
    #pragma unroll
    for (int s = 0; s < 8; ++s) { bestv[s] = 1e30f; secv[s] = 1e30f; besti[s] = 0; }

    {   // prime panel p0 -> buf 0 (16 KB: 16 x 1KB, 4 per wave)
        const char* gp = (const char*)Ep + (size_t)p0 * 16384;
        char* lp = (char*)&Bbuf[0][0];
        #pragma unroll
        for (int i = 0; i < 4; ++i)
            gl2lds16(gp + (w * 4 + i) * 1024 + lane * 16, lp + (w * 4 + i) * 1024);
    }
    __syncthreads();

    for (int i = 0; i < QTR_PANELS; ++i) {
        const int p   = p0 + i;
        const int buf = i & 1;
        if (i + 1 < QTR_PANELS) {
            const char* gp = (const char*)Ep + (size_t)(p + 1) * 16384;
            char* lp = (char*)&Bbuf[buf ^ 1][0];
            #pragma unroll
            for (int k = 0; k < 4; ++k)
                gl2lds16(gp + (w * 4 + k) * 1024 + lane * 16, lp + (w * 4 + k) * 1024);
        }

        const short* Bh = &Bbuf[buf][0];
        const short* Bl = &Bbuf[buf][4096];

        f32x4 acc[2];                  // [rt]
        acc[0] = (f32x4)(0.0f);
        acc[1] = (f32x4)(0.0f);

        #pragma unroll
        for (int ks = 0; ks < 8; ++ks) {
            const int g = ks * 4 + quad;
            bf16x8 bh = *(const bf16x8*)(Bh + (g * 16 + n) * 8);
            bf16x8 bl = *(const bf16x8*)(Bl + (g * 16 + n) * 8);
            #pragma unroll
            for (int rt = 0; rt < 2; ++rt) {
                acc[rt] = __builtin_amdgcn_mfma_f32_16x16x32_bf16(Ah[rt][ks], bh, acc[rt], 0, 0, 0);
                acc[rt] = __builtin_amdgcn_mfma_f32_16x16x32_bf16(Al[rt][ks], bh, acc[rt], 0, 0, 0);
                acc[rt] = __builtin_amdgcn_mfma_f32_16x16x32_bf16(Ah[rt][ks], bl, acc[rt], 0, 0, 0);
            }
        }

        const int code = p * 16 + n;
        const float eev = ee[code];
        #pragma unroll
        for (int rt = 0; rt < 2; ++rt)
            #pragma unroll
            for (int r = 0; r < 4; ++r) {
                float key = fmaf(-2.0f, acc[rt][r], eev);
                int s = rt * 4 + r;
                float nb = fminf(key, bestv[s]);
                secv[s]  = fminf(secv[s], fmaxf(key, bestv[s]));
                besti[s] = (key < bestv[s]) ? code : besti[s];
                bestv[s] = nb;
            }
        __syncthreads();
    }

    // top-2 merge across the 16 'n' lanes
    #pragma unroll
    for (int off = 1; off < 16; off <<= 1) {
        #pragma unroll
        for (int s = 0; s < 8; ++s) {
            float ov = __shfl_xor(bestv[s], off);
            int   oi = __shfl_xor(besti[s], off);
            float os = __shfl_xor(secv[s], off);
            bool owin = (ov < bestv[s]) || (ov == bestv[s] && oi < besti[s]);
            if (owin) { secv[s] = fminf(os, bestv[s]); bestv[s] = ov; besti[s] = oi; }
            else      { secv[s] = fminf(secv[s], ov); }
        }
    }

    if (n == 0) {
        #pragma unroll
        for (int s = 0; s < 8; ++s) {
            int rl  = w * 32 + (s >> 2) * 16 + quad * 4 + (s & 3);
            int row = row0 + rl;
            f2 bs; bs[0] = bestv[s]; bs[1] = secv[s];
            res_bs[(size_t)row * 4 + qtr]  = bs;
            res_idx[(size_t)row * 4 + qtr] = besti[s];
        }
    }
}

// -------- merge quarters: final bidx + EPS flagging --------
__global__ void merge_kernel(const f2* __restrict__ res_bs, const int* __restrict__ res_idx,
                             int* __restrict__ bidx, int* __restrict__ counter,
                             int2* __restrict__ list) {
    const int row = blockIdx.x * blockDim.x + threadIdx.x;
    if (row >= N_ROWS) return;
    f2 c0 = res_bs[(size_t)row * 4];
    float gb = c0[0], gs = c0[1];
    int gi = res_idx[(size_t)row * 4];
    #pragma unroll
    for (int q = 1; q < 4; ++q) {        // ascending quarter: lowest-index ties
        f2 cq = res_bs[(size_t)row * 4 + q];
        int iq = res_idx[(size_t)row * 4 + q];
        if (cq[0] < gb) { gs = fminf(cq[1], gb); gb = cq[0]; gi = iq; }
        else            { gs = fminf(gs, cq[0]); }
    }
    bidx[row] = gi;
    if (gs - gb <= EPS_MARGIN) {
        int pos = atomicAdd(counter, 1);
        if (pos < FB_CAP) list[pos] = make_int2(row, gi);
    }
}

// -------- gather + straight-through output + loss (same op order as R4-R6) --------
__global__ void gather_kernel(const float* __restrict__ X, const float* __restrict__ Et32,
                              const int* __restrict__ bidx, float* __restrict__ out,
                              double* __restrict__ loss_sum) {
    __shared__ int bl_[128];
    const int t    = threadIdx.x;
    const int row0 = blockIdx.x * 128;
    if (t < 128) bl_[t] = bidx[row0 + t];
    __syncthreads();
    double ls = 0.0;
    const int d = t;
    #pragma unroll 4
    for (int r = 0; r < 128; ++r) {
        int code = bl_[r];
        float q  = Et32[(size_t)code * D_DIM + d];
        float x  = X[(size_t)(row0 + r) * D_DIM + d];
        float dq = q - x;
        out[(size_t)(row0 + r) * D_DIM + d] = x + dq;
        ls += (double)dq * (double)dq;
    }
    #pragma unroll
    for (int off = 32; off > 0; off >>= 1)
        ls += __shfl_down(ls, off);
    if ((t & 63) == 0) atomicAdd(loss_sum, ls);
}

// -------- refine phase 1: fp64 keys over (row-chunk x 16 slices) --------
__global__ void refine1_kernel(const float* __restrict__ X, const float* __restrict__ E,
                               const int* __restrict__ counter, const int2* __restrict__ list,
                               double* __restrict__ res_v, int* __restrict__ res_i) {
    __shared__ float xt[D_DIM][FB_RPB];
    __shared__ int rows_sh[FB_RPB];
    __shared__ double wbv[4][FB_RPB];
    __shared__ int    wbi[4][FB_RPB];

    int nf = *counter; if (nf > FB_CAP) nf = FB_CAP;
    const int nchunks = (nf + FB_RPB - 1) / FB_RPB;
    const int nitems  = nchunks * RF_SLICES;
    const int t = threadIdx.x;

    for (int item = blockIdx.x; item < nitems; item += gridDim.x) {
        const int rc = item / RF_SLICES;
        const int sl = item % RF_SLICES;
        __syncthreads();
        if (t < FB_RPB) {
            int e = rc * FB_RPB + t;
            int2 ent = list[(e < nf) ? e : 0];
            rows_sh[t] = ent.x;
        }
        __syncthreads();
        #pragma unroll
        for (int j = 0; j < FB_RPB; ++j)
            xt[t][j] = X[(size_t)rows_sh[j] * D_DIM + t];
        __syncthreads();

        const int k0 = sl * 512 + t * 2;
        double s0[FB_RPB], s1[FB_RPB], q0 = 0.0, q1 = 0.0;
        #pragma unroll
        for (int j = 0; j < FB_RPB; ++j) { s0[j] = 0.0; s1[j] = 0.0; }
        for (int d = 0; d < D_DIM; ++d) {
            f2 ev = *(const f2*)(E + (size_t)d * K_CODES + k0);
            double e0d = (double)ev[0], e1d = (double)ev[1];
            const f4* xp = (const f4*)(&xt[d][0]);
            f4 xa = xp[0], xb = xp[1];
            double xd[FB_RPB] = { (double)xa[0], (double)xa[1], (double)xa[2], (double)xa[3],
                                  (double)xb[0], (double)xb[1], (double)xb[2], (double)xb[3] };
            q0 += e0d * e0d; q1 += e1d * e1d;
            #pragma unroll
            for (int j = 0; j < FB_RPB; ++j) {
                s0[j] += xd[j] * e0d;
                s1[j] += xd[j] * e1d;
            }
        }
        double bv[FB_RPB]; int bi[FB_RPB];
        #pragma unroll
        for (int j = 0; j < FB_RPB; ++j) {
            double k0v = q0 - 2.0 * s0[j];
            double k1v = q1 - 2.0 * s1[j];
            bv[j] = k0v; bi[j] = k0;
            if (k1v < bv[j]) { bv[j] = k1v; bi[j] = k0 + 1; }
        }
        #pragma unroll
        for (int off = 1; off < 64; off <<= 1) {
            #pragma unroll
            for (int j = 0; j < FB_RPB; ++j) {
                double ov = __shfl_xor(bv[j], off);
                int    oi = __shfl_xor(bi[j], off);
                if (ov < bv[j] || (ov == bv[j] && oi < bi[j])) { bv[j] = ov; bi[j] = oi; }
            }
        }
        const int wave = t >> 6;
        if ((t & 63) == 0) {
            #pragma unroll
            for (int j = 0; j < FB_RPB; ++j) { wbv[wave][j] = bv[j]; wbi[wave][j] = bi[j]; }
        }
        __syncthreads();
        if (t < FB_RPB) {
            double b = wbv[0][t]; int i_ = wbi[0][t];
            #pragma unroll
            for (int wv = 1; wv < 4; ++wv) {
                double ov = wbv[wv][t]; int oi = wbi[wv][t];
                if (ov < b || (ov == b && oi < i_)) { b = ov; i_ = oi; }
            }
            int e = rc * FB_RPB + t;
            res_v[(size_t)e * RF_SLICES + sl] = b;
            res_i[(size_t)e * RF_SLICES + sl] = i_;
        }
    }
}

// -------- refine phase 2: pick fp64 winner, patch row + loss --------
__global__ void patch_kernel(const float* __restrict__ X, const float* __restrict__ Et32,
                             float* __restrict__ out, double* __restrict__ loss_sum,
                             const int* __restrict__ counter, const int2* __restrict__ list,
                             const double* __restrict__ res_v, const int* __restrict__ res_i) {
    int nf = *counter; if (nf > FB_CAP) nf = FB_CAP;
    const int b = blockIdx.x;
    if (b >= nf) return;
    __shared__ int nc_sh;
    const int t = threadIdx.x;
    if (t == 0) {
        double bv = res_v[(size_t)b * RF_SLICES]; int bi = res_i[(size_t)b * RF_SLICES];
        for (int s = 1; s < RF_SLICES; ++s) {
            double v = res_v[(size_t)b * RF_SLICES + s];
            int    i = res_i[(size_t)b * RF_SLICES + s];
            if (v < bv || (v == bv && i < bi)) { bv = v; bi = i; }
        }
        nc_sh = bi;
    }
    __syncthreads();
    int2 ent = list[b];
    const int oc = ent.y, row = ent.x, nc = nc_sh;
    if (nc == oc) return;
    float x  = X[(size_t)row * D_DIM + t];
    float qn = Et32[(size_t)nc * D_DIM + t];
    float qo = Et32[(size_t)oc * D_DIM + t];
    float dqn = qn - x, dqo = qo - x;
    out[(size_t)row * D_DIM + t] = x + dqn;
    double dl = (double)dqn * dqn - (double)dqo * dqo;
    #pragma unroll
    for (int off = 32; off > 0; off >>= 1)
        dl += __shfl_down(dl, off);
    if ((t & 63) == 0) atomicAdd(loss_sum, dl);
}

// -------- finalize loss --------
__global__ void fin_kernel(const double* __restrict__ loss_sum, float* __restrict__ out) {
    double m = loss_sum[0] / (double)NUM_ELEM;
    out[NUM_ELEM] = (float)(0.25 * m + m);
}

extern "C" void kernel_launch(void* const* d_in, const int* in_sizes, int n_in,
                              void* d_out, int out_size, void* d_ws, size_t ws_size,
                              hipStream_t stream) {
    const float* X = (const float*)d_in[0];   // [32,1024,256] fp32
    const float* E = (const float*)d_in[1];   // [256,8192] fp32
    float* out = (float*)d_out;

    // ws layout (res_bs/res_idx are dead after merge -> reused as res_v/res_i)
    double* loss_sum = (double*)d_ws;                          // 8 B
    int*    counter  = (int*)((char*)d_ws + 8);                // 4 B
    float*  ee       = (float*)((char*)d_ws + 1024);           // 32 KB
    int2*   list     = (int2*)((char*)d_ws + 36864);           // 64 KB
    f2*     res_bs   = (f2*)((char*)d_ws + 131072);            // 1 MB (131072 x f2)
    double* res_v    = (double*)((char*)d_ws + 131072);        // aliases res_bs
    int*    res_idx  = (int*)((char*)d_ws + 1179648);          // 512 KB
    int*    res_i    = (int*)((char*)d_ws + 1179648);          // aliases res_idx
    int*    bidx     = (int*)((char*)d_ws + 1703936);          // 128 KB
    float*  Et32     = (float*)((char*)d_ws + 1835008);        // 8 MB
    short*  Ep       = (short*)((char*)d_ws + 10223616);       // 8 MB -> ends ~17.8 MB

    hipMemsetAsync(d_ws, 0, 1024, stream);
    prep_kernel<<<N_PANELS, 256, 0, stream>>>(E, Ep);
    trans32_kernel<<<dim3(128, 4), 256, 0, stream>>>(E, Et32);
    ee_kernel<<<K_CODES / 256, 256, 0, stream>>>(E, ee);
    mfma_sieve_kernel<<<1024, 256, 0, stream>>>(X, Ep, ee, res_bs, res_idx);
    merge_kernel<<<N_ROWS / 256, 256, 0, stream>>>(res_bs, res_idx, bidx, counter, list);
    gather_kernel<<<N_ROWS / 128, 256, 0, stream>>>(X, Et32, bidx, out, loss_sum);
    refine1_kernel<<<2048, 256, 0, stream>>>(X, E, counter, list, res_v, res_i);
    patch_kernel<<<FB_CAP, 256, 0, stream>>>(X, Et32, out, loss_sum, counter, list,
                                             res_v, res_i);
    fin_kernel<<<1, 1, 0, stream>>>(loss_sum, out);
}